// Round 6
// baseline (266.953 us; speedup 1.0000x reference)
//
#include <hip/hip_runtime.h>
#include <hip/hip_bf16.h>

#define VN 50000
#define RN 5
#define AN 8
#define CN 32
#define KSTEPS 40   // RN*AN
#define NB 8        // N-blocks of 16 (NTOT = 128 = n_rot*T)

typedef __attribute__((ext_vector_type(8))) short bf16x8;
typedef __attribute__((ext_vector_type(4))) float f32x4;
typedef __attribute__((ext_vector_type(2))) float f32x2;
typedef __attribute__((ext_vector_type(2))) int   i32x2;

__device__ __forceinline__ float b2f(short s) {
    union { unsigned u; float f; } cv;
    cv.u = ((unsigned)(unsigned short)s) << 16;
    return cv.f;
}
__device__ __forceinline__ short f2b(float f) {
    union { float f; unsigned u; } cv; cv.f = f;
    unsigned r = cv.u + 0x7fff + ((cv.u >> 16) & 1);   // RNE
    return (short)(r >> 16);
}

// f32 -> bf16 pack of the conv-1 input signal
__global__ void pack_x(const float* __restrict__ x, __hip_bfloat16* __restrict__ xb, int n4) {
    int i = blockIdx.x * blockDim.x + threadIdx.x;
    if (i >= n4) return;
    float4 v = ((const float4*)x)[i];
    ushort4 o;
    o.x = (unsigned short)f2b(v.x);
    o.y = (unsigned short)f2b(v.y);
    o.z = (unsigned short)f2b(v.z);
    o.w = (unsigned short)f2b(v.w);
    ((ushort4*)xb)[i] = o;
}

// Rolled templates -> MFMA-fragment-order bf16 matrices.
// Bp flat index = ((kstep*NB + nb)*64 + lane)*8 + j
// value = templ[t, r, (a - 2n) mod 8, c], k=(r*8+a)*32+c, nt=nb*16+(lane&15)
__global__ void build_Bp(const float* __restrict__ t1, const float* __restrict__ t2,
                         __hip_bfloat16* __restrict__ B1, __hip_bfloat16* __restrict__ B2) {
    int m = blockIdx.x * blockDim.x + threadIdx.x;
    if (m >= KSTEPS * NB * 64 * 8) return;
    int j = m & 7;
    int lane = (m >> 3) & 63;
    int nb = (m >> 9) & 7;
    int kstep = m >> 12;
    int c = ((lane >> 4) << 3) + j;
    int r = kstep >> 3, a = kstep & 7;
    int nt = nb * 16 + (lane & 15);
    int n = nt >> 5, t = nt & 31;
    int asrc = (a - 2 * n + 8) & 7;
    int src = ((t * RN + r) * AN + asrc) * CN + c;
    ((unsigned short*)B1)[m] = (unsigned short)f2b(t1[src]);
    ((unsigned short*)B2)[m] = (unsigned short)f2b(t2[src]);
}

// Fused gather + interp + GEMM + AngularMaxPool (+bias/residual/relu).
// 4 waves/block over the SAME 32 vertices; wave w owns a = {2w, 2w+1} for all r
// (K-split). Cross-wave K-sum via LDS tree, then epilogue by wave 0.
template<bool FIRST>
__global__ __launch_bounds__(256)
void conv_mfma(const __hip_bfloat16* __restrict__ xb,   // [V][32] bf16 input
               const int*   __restrict__ bc_idx,        // [V][120]
               const float* __restrict__ bc_w,          // [V][120]
               const __hip_bfloat16* __restrict__ Bp,   // fragment layout
               const float* __restrict__ bias,          // [32]
               const float* __restrict__ signal,        // residual f32 (conv2)
               __hip_bfloat16* __restrict__ out_bf,     // conv1 out (s1, bf16)
               float* __restrict__ out_f)               // conv2 out (f32)
{
    const int tid = threadIdx.x;
    const int wid = tid >> 6;            // 0..3 : K-split slice
    const int lane = tid & 63;
    const int vbase = blockIdx.x * 32;
    const int arow = lane & 15;
    const int c0 = (lane >> 4) << 3;

    int v0 = vbase + arow;   int vc0 = v0 < VN ? v0 : VN - 1;
    int v1 = v0 + 16;        int vc1 = v1 < VN ? v1 : VN - 1;

    const int*   ip0 = bc_idx + (size_t)vc0 * 120;
    const int*   ip1 = bc_idx + (size_t)vc1 * 120;
    const float* wp0 = bc_w   + (size_t)vc0 * 120;
    const float* wp1 = bc_w   + (size_t)vc1 * 120;
    const unsigned short* xs = (const unsigned short*)xb;
    const bf16x8* Bfrag = (const bf16x8*)Bp + lane;     // + (ks*NB+nb)*64

    f32x4 acc[2][NB];
#pragma unroll
    for (int mi = 0; mi < 2; ++mi)
#pragma unroll
        for (int nb = 0; nb < NB; ++nb) acc[mi][nb] = (f32x4)(0.f);

#pragma unroll
    for (int r = 0; r < RN; ++r) {
        // this wave's 6 idx + 6 w per vertex row: elements [r*24 + wid*6, +6)
        const int off = r * 24 + wid * 6;            // 8B-aligned
        i32x2 ia[3], ib[3]; f32x2 wa[3], wb[3];
#pragma unroll
        for (int q = 0; q < 3; ++q) {
            ia[q] = __builtin_nontemporal_load((const i32x2*)(ip0 + off) + q);
            ib[q] = __builtin_nontemporal_load((const i32x2*)(ip1 + off) + q);
            wa[q] = __builtin_nontemporal_load((const f32x2*)(wp0 + off) + q);
            wb[q] = __builtin_nontemporal_load((const f32x2*)(wp1 + off) + q);
        }
#pragma unroll
        for (int h = 0; h < 2; ++h) {
            bf16x8 g0a = *(const bf16x8*)(xs + (size_t)ia[(3*h+0)>>1][(3*h+0)&1] * CN + c0);
            bf16x8 g1a = *(const bf16x8*)(xs + (size_t)ia[(3*h+1)>>1][(3*h+1)&1] * CN + c0);
            bf16x8 g2a = *(const bf16x8*)(xs + (size_t)ia[(3*h+2)>>1][(3*h+2)&1] * CN + c0);
            bf16x8 g0b = *(const bf16x8*)(xs + (size_t)ib[(3*h+0)>>1][(3*h+0)&1] * CN + c0);
            bf16x8 g1b = *(const bf16x8*)(xs + (size_t)ib[(3*h+1)>>1][(3*h+1)&1] * CN + c0);
            bf16x8 g2b = *(const bf16x8*)(xs + (size_t)ib[(3*h+2)>>1][(3*h+2)&1] * CN + c0);
            float w0a = wa[(3*h+0)>>1][(3*h+0)&1], w1a = wa[(3*h+1)>>1][(3*h+1)&1], w2a = wa[(3*h+2)>>1][(3*h+2)&1];
            float w0b = wb[(3*h+0)>>1][(3*h+0)&1], w1b = wb[(3*h+1)>>1][(3*h+1)&1], w2b = wb[(3*h+2)>>1][(3*h+2)&1];
            bf16x8 af0, af1;
#pragma unroll
            for (int j = 0; j < 8; ++j) {
                float fa = fmaf(w0a, b2f(g0a[j]), fmaf(w1a, b2f(g1a[j]), w2a * b2f(g2a[j])));
                float fb = fmaf(w0b, b2f(g0b[j]), fmaf(w1b, b2f(g1b[j]), w2b * b2f(g2b[j])));
                af0[j] = f2b(fa);
                af1[j] = f2b(fb);
            }
            const int ks = r * AN + 2 * wid + h;
#pragma unroll
            for (int nb = 0; nb < NB; ++nb) {
                bf16x8 bfr = Bfrag[(ks * NB + nb) * 64];
                acc[0][nb] = __builtin_amdgcn_mfma_f32_16x16x32_bf16(af0, bfr, acc[0][nb], 0, 0, 0);
                acc[1][nb] = __builtin_amdgcn_mfma_f32_16x16x32_bf16(af1, bfr, acc[1][nb], 0, 0, 0);
            }
        }
    }

    // ---- cross-wave K reduction: [buf][frag][lane] f32x4, lane-contiguous b128 ----
    __shared__ f32x4 red[2][16][64];    // 32 KB
    if (wid >= 2) {
#pragma unroll
        for (int mi = 0; mi < 2; ++mi)
#pragma unroll
            for (int nb = 0; nb < NB; ++nb)
                red[wid - 2][mi * 8 + nb][lane] = acc[mi][nb];
    }
    __syncthreads();
    if (wid < 2) {
#pragma unroll
        for (int mi = 0; mi < 2; ++mi)
#pragma unroll
            for (int nb = 0; nb < NB; ++nb)
                acc[mi][nb] += red[wid][mi * 8 + nb][lane];
    }
    __syncthreads();
    if (wid == 1) {
#pragma unroll
        for (int mi = 0; mi < 2; ++mi)
#pragma unroll
            for (int nb = 0; nb < NB; ++nb)
                red[0][mi * 8 + nb][lane] = acc[mi][nb];
    }
    __syncthreads();
    if (wid != 0) return;
#pragma unroll
    for (int mi = 0; mi < 2; ++mi)
#pragma unroll
        for (int nb = 0; nb < NB; ++nb)
            acc[mi][nb] += red[0][mi * 8 + nb][lane];

    // ---- epilogue (wave 0): AMP over n in-register, bias (+residual) + relu ----
    const int colD = lane & 15;
    const int rbase = (lane >> 4) << 2;
#pragma unroll
    for (int mi = 0; mi < 2; ++mi) {
#pragma unroll
        for (int q = 0; q < 2; ++q) {
            f32x4 mx;
#pragma unroll
            for (int rg = 0; rg < 4; ++rg)
                mx[rg] = fmaxf(fmaxf(acc[mi][q][rg], acc[mi][q + 2][rg]),
                               fmaxf(acc[mi][q + 4][rg], acc[mi][q + 6][rg]));
            int t = q * 16 + colD;
            float b = bias[t];
#pragma unroll
            for (int rg = 0; rg < 4; ++rg) {
                int vv = vbase + mi * 16 + rbase + rg;
                if (vv < VN) {
                    float val = mx[rg] + b;
                    if (FIRST) {
                        ((unsigned short*)out_bf)[vv * CN + t] =
                            (unsigned short)f2b(fmaxf(val, 0.f));   // reused -> keep in L2
                    } else {
                        val += __builtin_nontemporal_load(signal + vv * CN + t);
                        __builtin_nontemporal_store(fmaxf(val, 0.f), out_f + vv * CN + t);
                    }
                }
            }
        }
    }
}

extern "C" void kernel_launch(void* const* d_in, const int* in_sizes, int n_in,
                              void* d_out, int out_size, void* d_ws, size_t ws_size,
                              hipStream_t stream) {
    const float* signal = (const float*)d_in[0];
    const int*   bc_idx = (const int*)d_in[1];
    const float* bc_w   = (const float*)d_in[2];
    const float* t1     = (const float*)d_in[3];
    const float* b1     = (const float*)d_in[4];
    const float* t2     = (const float*)d_in[5];
    const float* b2     = (const float*)d_in[6];
    float* out = (float*)d_out;

    __hip_bfloat16* ws = (__hip_bfloat16*)d_ws;
    __hip_bfloat16* xb  = ws;                       // V*32 bf16
    __hip_bfloat16* s1  = ws + VN * CN;             // V*32 bf16
    __hip_bfloat16* Bp1 = ws + 2 * VN * CN;         // 163840 bf16
    __hip_bfloat16* Bp2 = Bp1 + KSTEPS * NB * 64 * 8;
    // total ws use ~= 7.0 MB

    pack_x<<<(VN * CN / 4 + 255) / 256, 256, 0, stream>>>(signal, xb, VN * CN / 4);
    build_Bp<<<(KSTEPS * NB * 64 * 8) / 256, 256, 0, stream>>>(t1, t2, Bp1, Bp2);

    int blocks = (VN + 31) / 32;   // 4 waves/block (K-split), 32 v/block
    conv_mfma<true ><<<blocks, 256, 0, stream>>>(xb, bc_idx, bc_w, Bp1, b1, nullptr, s1, nullptr);
    conv_mfma<false><<<blocks, 256, 0, stream>>>(s1, bc_idx, bc_w, Bp2, b2, signal, nullptr, out);
}

// Round 7
// 260.995 us; speedup vs baseline: 1.0228x; 1.0228x over previous
//
#include <hip/hip_runtime.h>
#include <hip/hip_bf16.h>

#define VN 50000
#define RN 5
#define AN 8
#define CN 32
#define NB 8        // N-blocks of 16 (NTOT = 128 = n_rot*T)
#define MT 32       // vertices per block

typedef short bf16x8  __attribute__((ext_vector_type(8)));
typedef short bf16x16 __attribute__((ext_vector_type(16)));
typedef float f32x4   __attribute__((ext_vector_type(4)));

__device__ __forceinline__ float b2f(short s) {
    union { unsigned u; float f; } cv;
    cv.u = ((unsigned)(unsigned short)s) << 16;
    return cv.f;
}
__device__ __forceinline__ short f2b(float f) {
    union { float f; unsigned u; } cv; cv.f = f;
    unsigned r = cv.u + 0x7fff + ((cv.u >> 16) & 1);   // RNE
    return (short)(r >> 16);
}

// f32 -> bf16 pack of the conv-1 input signal
__global__ void pack_x(const float* __restrict__ x, __hip_bfloat16* __restrict__ xb, int n4) {
    int i = blockIdx.x * blockDim.x + threadIdx.x;
    if (i >= n4) return;
    float4 v = ((const float4*)x)[i];
    ushort4 o;
    o.x = (unsigned short)f2b(v.x);
    o.y = (unsigned short)f2b(v.y);
    o.z = (unsigned short)f2b(v.z);
    o.w = (unsigned short)f2b(v.w);
    ((ushort4*)xb)[i] = o;
}

// Rolled templates -> MFMA-fragment-order bf16 matrices.
// Bp flat index = ((kstep*NB + nb)*64 + lane)*8 + j
// value = templ[t, r, (a - 2n) mod 8, c], k=(r*8+a)*32+c, nt=nb*16+(lane&15)
__global__ void build_Bp(const float* __restrict__ t1, const float* __restrict__ t2,
                         __hip_bfloat16* __restrict__ B1, __hip_bfloat16* __restrict__ B2) {
    int m = blockIdx.x * blockDim.x + threadIdx.x;
    if (m >= RN * AN * NB * 64 * 8) return;
    int j = m & 7;
    int lane = (m >> 3) & 63;
    int nb = (m >> 9) & 7;
    int kstep = m >> 12;
    int c = ((lane >> 4) << 3) + j;
    int r = kstep >> 3, a = kstep & 7;
    int nt = nb * 16 + (lane & 15);
    int n = nt >> 5, t = nt & 31;
    int asrc = (a - 2 * n + 8) & 7;
    int src = ((t * RN + r) * AN + asrc) * CN + c;
    ((unsigned short*)B1)[m] = (unsigned short)f2b(t1[src]);
    ((unsigned short*)B2)[m] = (unsigned short)f2b(t2[src]);
}

// Two-phase fused conv: per r, (A) 128 threads cooperatively gather+blend the
// [32 x 256] bf16 interp tile into swizzled LDS (wide independent gathers),
// (B) 2 waves MFMA from LDS (wave owns 4 of 8 nb columns).
// AMP: per-wave partial max + cross-wave LDS max. +bias/residual/relu.
template<bool FIRST>
__global__ __launch_bounds__(128)
void conv_fused(const __hip_bfloat16* __restrict__ xb,   // [V][32] bf16 input
                const int*   __restrict__ bc_idx,        // [V][120]
                const float* __restrict__ bc_w,          // [V][120]
                const __hip_bfloat16* __restrict__ Bp,   // fragment layout
                const float* __restrict__ bias,          // [32]
                const float* __restrict__ signal,        // residual f32 (conv2)
                __hip_bfloat16* __restrict__ out_bf,     // conv1 out (s1, bf16)
                float* __restrict__ out_f)               // conv2 out (f32)
{
    __shared__ __align__(16) unsigned char smraw[16384];
    const int tid = threadIdx.x;
    const int wid = tid >> 6;
    const int lane = tid & 63;
    const int vbase = blockIdx.x * MT;
    const unsigned short* xs = (const unsigned short*)xb;

    const int arow = lane & 15;      // A-frag row
    const int c0q = lane >> 4;       // 16B chunk (8 channels)

    f32x4 acc[2][4];
#pragma unroll
    for (int mi = 0; mi < 2; ++mi)
#pragma unroll
        for (int j = 0; j < 4; ++j) acc[mi][j] = (f32x4)(0.f);

    for (int r = 0; r < RN; ++r) {
        if (r) __syncthreads();      // protect LDS from prev phase-B readers

        // ---- phase A: gather + blend -> LDS tile [32 v][256 k] bf16, swizzled ----
        // item id = (v<<4) | (a<<1) | h : half-row (16 channels) of one (v,a)
#pragma unroll
        for (int k = 0; k < 4; ++k) {
            int id = tid + k * 128;
            int vl = id >> 4, a = (id >> 1) & 7, h = id & 1;
            int vg = vbase + vl;
            int vc = vg < VN ? vg : VN - 1;
            const int*   ip = bc_idx + (size_t)vc * 120 + r * 24 + a * 3;
            const float* wp = bc_w   + (size_t)vc * 120 + r * 24 + a * 3;
            int   i0 = __builtin_nontemporal_load(ip);
            int   i1 = __builtin_nontemporal_load(ip + 1);
            int   i2 = __builtin_nontemporal_load(ip + 2);
            float w0 = __builtin_nontemporal_load(wp);
            float w1 = __builtin_nontemporal_load(wp + 1);
            float w2 = __builtin_nontemporal_load(wp + 2);
            bf16x16 g0 = *(const bf16x16*)(xs + (size_t)i0 * CN + h * 16);
            bf16x16 g1 = *(const bf16x16*)(xs + (size_t)i1 * CN + h * 16);
            bf16x16 g2 = *(const bf16x16*)(xs + (size_t)i2 * CN + h * 16);
            bf16x8 ch[2];
#pragma unroll
            for (int j = 0; j < 16; ++j) {
                float f = fmaf(w0, b2f(g0[j]), fmaf(w1, b2f(g1[j]), w2 * b2f(g2[j])));
                ch[j >> 3][j & 7] = f2b(f);
            }
#pragma unroll
            for (int qq = 0; qq < 2; ++qq) {
                int q = h * 2 + qq;                      // 16B chunk 0..3 (channels q*8..)
                int baddr = vl * 512 + ((a * 64 + q * 16) ^ ((vl & 7) << 4));
                *(bf16x8*)(smraw + baddr) = ch[qq];
            }
        }
        __syncthreads();

        // ---- phase B: MFMA from LDS; wave owns nb = wid*4 .. wid*4+3 ----
#pragma unroll
        for (int ks = 0; ks < 8; ++ks) {
            bf16x8 af[2];
#pragma unroll
            for (int mi = 0; mi < 2; ++mi) {
                int row = mi * 16 + arow;
                int baddr = row * 512 + ((ks * 64 + c0q * 16) ^ ((row & 7) << 4));
                af[mi] = *(const bf16x8*)(smraw + baddr);
            }
            int gks = r * 8 + ks;
#pragma unroll
            for (int j = 0; j < 4; ++j) {
                int nb = wid * 4 + j;
                bf16x8 bfr = *(const bf16x8*)((const unsigned short*)Bp +
                                ((size_t)(gks * NB + nb) * 64 + lane) * 8);
                acc[0][j] = __builtin_amdgcn_mfma_f32_16x16x32_bf16(af[0], bfr, acc[0][j], 0, 0, 0);
                acc[1][j] = __builtin_amdgcn_mfma_f32_16x16x32_bf16(af[1], bfr, acc[1][j], 0, 0, 0);
            }
        }
    }

    // ---- AMP: per-wave partial max over this wave's 2 n's, then cross-wave ----
    __syncthreads();                 // phase-B readers done; reuse LDS for reduction
    f32x4* redp = (f32x4*)smraw;     // [w 2][mi 2][q 2][lane 64] = 8 KB
#pragma unroll
    for (int mi = 0; mi < 2; ++mi)
#pragma unroll
        for (int q = 0; q < 2; ++q) {
            f32x4 pm;
#pragma unroll
            for (int rg = 0; rg < 4; ++rg)
                pm[rg] = fmaxf(acc[mi][q][rg], acc[mi][q + 2][rg]);   // nb=q, q+2 -> same t-half
            redp[((wid * 2 + mi) * 2 + q) * 64 + lane] = pm;
        }
    __syncthreads();

    // ---- epilogue: wave wid handles mfrag mi=wid; bias(+residual)+relu+store ----
    const int colD = lane & 15;
    const int rbase = (lane >> 4) << 2;
#pragma unroll
    for (int q = 0; q < 2; ++q) {
        f32x4 m0 = redp[((0 * 2 + wid) * 2 + q) * 64 + lane];
        f32x4 m1 = redp[((1 * 2 + wid) * 2 + q) * 64 + lane];
        int t = q * 16 + colD;
        float b = bias[t];
#pragma unroll
        for (int rg = 0; rg < 4; ++rg) {
            int vv = vbase + wid * 16 + rbase + rg;
            if (vv < VN) {
                float val = fmaxf(m0[rg], m1[rg]) + b;
                if (FIRST) {
                    ((unsigned short*)out_bf)[vv * CN + t] =
                        (unsigned short)f2b(fmaxf(val, 0.f));   // reused by conv2 -> keep in L2
                } else {
                    val += __builtin_nontemporal_load(signal + vv * CN + t);
                    __builtin_nontemporal_store(fmaxf(val, 0.f), out_f + vv * CN + t);
                }
            }
        }
    }
}

extern "C" void kernel_launch(void* const* d_in, const int* in_sizes, int n_in,
                              void* d_out, int out_size, void* d_ws, size_t ws_size,
                              hipStream_t stream) {
    const float* signal = (const float*)d_in[0];
    const int*   bc_idx = (const int*)d_in[1];
    const float* bc_w   = (const float*)d_in[2];
    const float* t1     = (const float*)d_in[3];
    const float* b1     = (const float*)d_in[4];
    const float* t2     = (const float*)d_in[5];
    const float* b2     = (const float*)d_in[6];
    float* out = (float*)d_out;

    __hip_bfloat16* ws = (__hip_bfloat16*)d_ws;
    __hip_bfloat16* xb  = ws;                       // V*32 bf16
    __hip_bfloat16* s1  = ws + VN * CN;             // V*32 bf16
    __hip_bfloat16* Bp1 = ws + 2 * VN * CN;         // 163840 bf16
    __hip_bfloat16* Bp2 = Bp1 + RN * AN * NB * 64 * 8;
    // total ws use ~= 7.0 MB

    pack_x<<<(VN * CN / 4 + 255) / 256, 256, 0, stream>>>(signal, xb, VN * CN / 4);
    build_Bp<<<(RN * AN * NB * 64 * 8) / 256, 256, 0, stream>>>(t1, t2, Bp1, Bp2);

    int blocks = (VN + MT - 1) / MT;   // 1563 blocks, 128 threads (2 waves)
    conv_fused<true ><<<blocks, 128, 0, stream>>>(xb, bc_idx, bc_w, Bp1, b1, nullptr, s1, nullptr);
    conv_fused<false><<<blocks, 128, 0, stream>>>(s1, bc_idx, bc_w, Bp2, b2, signal, nullptr, out);
}

// Round 8
// 228.159 us; speedup vs baseline: 1.1700x; 1.1439x over previous
//
#include <hip/hip_runtime.h>
#include <hip/hip_bf16.h>

#define VN 50000
#define RN 5
#define AN 8
#define CN 32
#define NB 8        // N-blocks of 16 (NTOT = 128 = n_rot*T)
#define MT 32       // vertices per block

typedef short bf16x8  __attribute__((ext_vector_type(8)));
typedef short bf16x16 __attribute__((ext_vector_type(16)));
typedef float f32x4   __attribute__((ext_vector_type(4)));
typedef int   i32x4   __attribute__((ext_vector_type(4)));

__device__ __forceinline__ float b2f(short s) {
    union { unsigned u; float f; } cv;
    cv.u = ((unsigned)(unsigned short)s) << 16;
    return cv.f;
}
__device__ __forceinline__ short f2b(float f) {
    union { float f; unsigned u; } cv; cv.f = f;
    unsigned r = cv.u + 0x7fff + ((cv.u >> 16) & 1);   // RNE
    return (short)(r >> 16);
}

// f32 -> bf16 pack of the conv-1 input signal
__global__ void pack_x(const float* __restrict__ x, __hip_bfloat16* __restrict__ xb, int n4) {
    int i = blockIdx.x * blockDim.x + threadIdx.x;
    if (i >= n4) return;
    float4 v = ((const float4*)x)[i];
    ushort4 o;
    o.x = (unsigned short)f2b(v.x);
    o.y = (unsigned short)f2b(v.y);
    o.z = (unsigned short)f2b(v.z);
    o.w = (unsigned short)f2b(v.w);
    ((ushort4*)xb)[i] = o;
}

// Rolled templates -> MFMA-fragment-order bf16 matrices.
// Bp flat index = ((kstep*NB + nb)*64 + lane)*8 + j
// value = templ[t, r, (a - 2n) mod 8, c], k=(r*8+a)*32+c, nt=nb*16+(lane&15)
__global__ void build_Bp(const float* __restrict__ t1, const float* __restrict__ t2,
                         __hip_bfloat16* __restrict__ B1, __hip_bfloat16* __restrict__ B2) {
    int m = blockIdx.x * blockDim.x + threadIdx.x;
    if (m >= RN * AN * NB * 64 * 8) return;
    int j = m & 7;
    int lane = (m >> 3) & 63;
    int nb = (m >> 9) & 7;
    int kstep = m >> 12;
    int c = ((lane >> 4) << 3) + j;
    int r = kstep >> 3, a = kstep & 7;
    int nt = nb * 16 + (lane & 15);
    int n = nt >> 5, t = nt & 31;
    int asrc = (a - 2 * n + 8) & 7;
    int src = ((t * RN + r) * AN + asrc) * CN + c;
    ((unsigned short*)B1)[m] = (unsigned short)f2b(t1[src]);
    ((unsigned short*)B2)[m] = (unsigned short)f2b(t2[src]);
}

// Two-phase fused conv with a software-pipelined gather front-end:
//  thread owns (vertex vl, half-row h, a-quad as); per r it issues 12
//  independent 32B gathers into named regs (sched_barrier-pinned), idx
//  prefetched 2 r ahead, w 1 r ahead, gathers for r+1 issued before phase B.
template<bool FIRST>
__global__ __launch_bounds__(128, 2)
void conv_fused(const __hip_bfloat16* __restrict__ xb,   // [V][32] bf16 input
                const int*   __restrict__ bc_idx,        // [V][120]
                const float* __restrict__ bc_w,          // [V][120]
                const __hip_bfloat16* __restrict__ Bp,   // fragment layout
                const float* __restrict__ bias,          // [32]
                const float* __restrict__ signal,        // residual f32 (conv2)
                __hip_bfloat16* __restrict__ out_bf,     // conv1 out (s1, bf16)
                float* __restrict__ out_f)               // conv2 out (f32)
{
    __shared__ __align__(16) unsigned char smraw[16384];
    const int tid = threadIdx.x;
    const int wid = tid >> 6;            // also the a-quad "as"
    const int lane = tid & 63;
    const int vl = tid & 31;             // vertex within tile
    const int h  = (tid >> 5) & 1;       // half-row (16 channels)
    const int vbase = blockIdx.x * MT;
    const unsigned short* xs = (const unsigned short*)xb;

    int vg = vbase + vl;
    int vc = vg < VN ? vg : VN - 1;
    const size_t ibase = (size_t)vc * 120 + wid * 12;   // + r*24, in ints

    const int arow = lane & 15;      // phase-B A-frag row
    const int c0q = lane >> 4;       // phase-B 16B chunk

    f32x4 acc[2][4];
#pragma unroll
    for (int mi = 0; mi < 2; ++mi)
#pragma unroll
        for (int j = 0; j < 4; ++j) acc[mi][j] = (f32x4)(0.f);

    i32x4 I[2][3];      // idx slots, rotate: slot r&1 holds r's 12 indices
    f32x4 Wv[2][3];     // w slots, 1 ahead
    bf16x16 G[12];      // in-flight gathers (96 VGPR, held live)

    // ---------------- prologue: I(0), I(1), W(0); issue G(0) ----------------
#pragma unroll
    for (int q = 0; q < 3; ++q) {
        I[0][q]  = __builtin_nontemporal_load((const i32x4*)(bc_idx + ibase) + q);
        I[1][q]  = __builtin_nontemporal_load((const i32x4*)(bc_idx + ibase + 24) + q);
        Wv[0][q] = __builtin_nontemporal_load((const f32x4*)(bc_w  + ibase) + q);
    }
    __builtin_amdgcn_sched_barrier(0);
#pragma unroll
    for (int e = 0; e < 12; ++e) {
        int idx = I[0][e >> 2][e & 3];
        G[e] = *(const bf16x16*)(xs + (size_t)idx * CN + h * 16);
    }
    __builtin_amdgcn_sched_barrier(0);

#pragma unroll
    for (int r = 0; r < RN; ++r) {
        // -- prefetch idx (r+2) and w (r+1): issue-only, pinned above consume --
        if (r + 2 < RN) {
#pragma unroll
            for (int q = 0; q < 3; ++q)
                I[r & 1][q] = __builtin_nontemporal_load(
                    (const i32x4*)(bc_idx + ibase + (r + 2) * 24) + q);
        }
        if (r + 1 < RN) {
#pragma unroll
            for (int q = 0; q < 3; ++q)
                Wv[(r + 1) & 1][q] = __builtin_nontemporal_load(
                    (const f32x4*)(bc_w + ibase + (r + 1) * 24) + q);
        }
        __builtin_amdgcn_sched_barrier(0);

        // -- consume: blend G(r) -> swizzled LDS tile [32 v][256 k] bf16 --
#pragma unroll
        for (int aa = 0; aa < 4; ++aa) {
            const int a = wid * 4 + aa;
            float w0 = Wv[r & 1][(aa * 3 + 0) >> 2][(aa * 3 + 0) & 3];
            float w1 = Wv[r & 1][(aa * 3 + 1) >> 2][(aa * 3 + 1) & 3];
            float w2 = Wv[r & 1][(aa * 3 + 2) >> 2][(aa * 3 + 2) & 3];
            bf16x8 ch[2];
#pragma unroll
            for (int j = 0; j < 16; ++j) {
                float f = fmaf(w0, b2f(G[aa * 3 + 0][j]),
                         fmaf(w1, b2f(G[aa * 3 + 1][j]),
                               w2 * b2f(G[aa * 3 + 2][j])));
                ch[j >> 3][j & 7] = f2b(f);
            }
#pragma unroll
            for (int qq = 0; qq < 2; ++qq) {
                int baddr = vl * 512 + ((a * 64 + h * 32 + qq * 16) ^ ((vl & 7) << 4));
                *(bf16x8*)(smraw + baddr) = ch[qq];
            }
        }
        __syncthreads();

        // -- issue gathers for r+1 (fly during phase B) --
        if (r + 1 < RN) {
#pragma unroll
            for (int e = 0; e < 12; ++e) {
                int idx = I[(r + 1) & 1][e >> 2][e & 3];
                G[e] = *(const bf16x16*)(xs + (size_t)idx * CN + h * 16);
            }
            __builtin_amdgcn_sched_barrier(0);
        }

        // -- phase B: MFMA from LDS; wave owns nb = wid*4 .. wid*4+3 --
#pragma unroll
        for (int ks = 0; ks < 8; ++ks) {
            bf16x8 af[2];
#pragma unroll
            for (int mi = 0; mi < 2; ++mi) {
                int row = mi * 16 + arow;
                int baddr = row * 512 + ((ks * 64 + c0q * 16) ^ ((row & 7) << 4));
                af[mi] = *(const bf16x8*)(smraw + baddr);
            }
            int gks = r * 8 + ks;
#pragma unroll
            for (int j = 0; j < 4; ++j) {
                int nb = wid * 4 + j;
                bf16x8 bfr = *(const bf16x8*)((const unsigned short*)Bp +
                                ((size_t)(gks * NB + nb) * 64 + lane) * 8);
                acc[0][j] = __builtin_amdgcn_mfma_f32_16x16x32_bf16(af[0], bfr, acc[0][j], 0, 0, 0);
                acc[1][j] = __builtin_amdgcn_mfma_f32_16x16x32_bf16(af[1], bfr, acc[1][j], 0, 0, 0);
            }
        }
        __syncthreads();
    }

    // ---- AMP: per-wave partial max over this wave's 2 n's, then cross-wave ----
    f32x4* redp = (f32x4*)smraw;     // [w 2][mi 2][q 2][lane 64] = 8 KB
#pragma unroll
    for (int mi = 0; mi < 2; ++mi)
#pragma unroll
        for (int q = 0; q < 2; ++q) {
            f32x4 pm;
#pragma unroll
            for (int rg = 0; rg < 4; ++rg)
                pm[rg] = fmaxf(acc[mi][q][rg], acc[mi][q + 2][rg]);   // nb=q, q+2 -> same t-half
            redp[((wid * 2 + mi) * 2 + q) * 64 + lane] = pm;
        }
    __syncthreads();

    // ---- epilogue: wave wid handles mfrag mi=wid; bias(+residual)+relu+store ----
    const int colD = lane & 15;
    const int rbase = (lane >> 4) << 2;
#pragma unroll
    for (int q = 0; q < 2; ++q) {
        f32x4 m0 = redp[((0 * 2 + wid) * 2 + q) * 64 + lane];
        f32x4 m1 = redp[((1 * 2 + wid) * 2 + q) * 64 + lane];
        int t = q * 16 + colD;
        float b = bias[t];
#pragma unroll
        for (int rg = 0; rg < 4; ++rg) {
            int vv = vbase + wid * 16 + rbase + rg;
            if (vv < VN) {
                float val = fmaxf(m0[rg], m1[rg]) + b;
                if (FIRST) {
                    ((unsigned short*)out_bf)[vv * CN + t] =
                        (unsigned short)f2b(fmaxf(val, 0.f));   // reused by conv2 -> keep in L2
                } else {
                    val += __builtin_nontemporal_load(signal + vv * CN + t);
                    __builtin_nontemporal_store(fmaxf(val, 0.f), out_f + vv * CN + t);
                }
            }
        }
    }
}

extern "C" void kernel_launch(void* const* d_in, const int* in_sizes, int n_in,
                              void* d_out, int out_size, void* d_ws, size_t ws_size,
                              hipStream_t stream) {
    const float* signal = (const float*)d_in[0];
    const int*   bc_idx = (const int*)d_in[1];
    const float* bc_w   = (const float*)d_in[2];
    const float* t1     = (const float*)d_in[3];
    const float* b1     = (const float*)d_in[4];
    const float* t2     = (const float*)d_in[5];
    const float* b2     = (const float*)d_in[6];
    float* out = (float*)d_out;

    __hip_bfloat16* ws = (__hip_bfloat16*)d_ws;
    __hip_bfloat16* xb  = ws;                       // V*32 bf16
    __hip_bfloat16* s1  = ws + VN * CN;             // V*32 bf16
    __hip_bfloat16* Bp1 = ws + 2 * VN * CN;         // 163840 bf16
    __hip_bfloat16* Bp2 = Bp1 + RN * AN * NB * 64 * 8;
    // total ws use ~= 7.0 MB

    pack_x<<<(VN * CN / 4 + 255) / 256, 256, 0, stream>>>(signal, xb, VN * CN / 4);
    build_Bp<<<(RN * AN * NB * 64 * 8) / 256, 256, 0, stream>>>(t1, t2, Bp1, Bp2);

    int blocks = (VN + MT - 1) / MT;   // 1563 blocks, 128 threads (2 waves)
    conv_fused<true ><<<blocks, 128, 0, stream>>>(xb, bc_idx, bc_w, Bp1, b1, nullptr, s1, nullptr);
    conv_fused<false><<<blocks, 128, 0, stream>>>(s1, bc_idx, bc_w, Bp2, b2, signal, nullptr, out);
}

// Round 9
// 222.312 us; speedup vs baseline: 1.2008x; 1.0263x over previous
//
#include <hip/hip_runtime.h>
#include <hip/hip_bf16.h>

#define VN 50000
#define RN 5
#define AN 8
#define CN 32
#define NB 8        // N-blocks of 16 (NTOT = 128 = n_rot*T)
#define MT 16       // vertices per block (50000 = 16*3125, no tail)

typedef short bf16x8  __attribute__((ext_vector_type(8)));
typedef short bf16x16 __attribute__((ext_vector_type(16)));
typedef float f32x4   __attribute__((ext_vector_type(4)));
typedef float f32x2   __attribute__((ext_vector_type(2)));
typedef int   i32x2   __attribute__((ext_vector_type(2)));

__device__ __forceinline__ float b2f(short s) {
    union { unsigned u; float f; } cv;
    cv.u = ((unsigned)(unsigned short)s) << 16;
    return cv.f;
}
__device__ __forceinline__ short f2b(float f) {
    union { float f; unsigned u; } cv; cv.f = f;
    unsigned r = cv.u + 0x7fff + ((cv.u >> 16) & 1);   // RNE
    return (short)(r >> 16);
}

// f32 -> bf16 pack of the conv-1 input signal
__global__ void pack_x(const float* __restrict__ x, __hip_bfloat16* __restrict__ xb, int n4) {
    int i = blockIdx.x * blockDim.x + threadIdx.x;
    if (i >= n4) return;
    float4 v = ((const float4*)x)[i];
    ushort4 o;
    o.x = (unsigned short)f2b(v.x);
    o.y = (unsigned short)f2b(v.y);
    o.z = (unsigned short)f2b(v.z);
    o.w = (unsigned short)f2b(v.w);
    ((ushort4*)xb)[i] = o;
}

// Rolled templates -> MFMA-fragment-order bf16 matrices.
// Bp flat index = ((kstep*NB + nb)*64 + lane)*8 + j
// value = templ[t, r, (a - 2n) mod 8, c], k=(r*8+a)*32+c, nt=nb*16+(lane&15)
__global__ void build_Bp(const float* __restrict__ t1, const float* __restrict__ t2,
                         __hip_bfloat16* __restrict__ B1, __hip_bfloat16* __restrict__ B2) {
    int m = blockIdx.x * blockDim.x + threadIdx.x;
    if (m >= RN * AN * NB * 64 * 8) return;
    int j = m & 7;
    int lane = (m >> 3) & 63;
    int nb = (m >> 9) & 7;
    int kstep = m >> 12;
    int c = ((lane >> 4) << 3) + j;
    int r = kstep >> 3, a = kstep & 7;
    int nt = nb * 16 + (lane & 15);
    int n = nt >> 5, t = nt & 31;
    int asrc = (a - 2 * n + 8) & 7;
    int src = ((t * RN + r) * AN + asrc) * CN + c;
    ((unsigned short*)B1)[m] = (unsigned short)f2b(t1[src]);
    ((unsigned short*)B2)[m] = (unsigned short)f2b(t2[src]);
}

// Two-phase fused conv, MT=16 variant (2x grid vs R8 for occupancy).
// Thread owns (vertex vl 0..15, half h, a-pair as 0..3): per r it issues 6
// independent 32B gathers into named regs (sched_barrier-pinned), idx
// prefetched 2 r ahead, w 1 r ahead, gathers for r+1 issued before phase B.
template<bool FIRST>
__global__ __launch_bounds__(128, 4)
void conv_fused(const __hip_bfloat16* __restrict__ xb,   // [V][32] bf16 input
                const int*   __restrict__ bc_idx,        // [V][120]
                const float* __restrict__ bc_w,          // [V][120]
                const __hip_bfloat16* __restrict__ Bp,   // fragment layout
                const float* __restrict__ bias,          // [32]
                const float* __restrict__ signal,        // residual f32 (conv2)
                __hip_bfloat16* __restrict__ out_bf,     // conv1 out (s1, bf16)
                float* __restrict__ out_f)               // conv2 out (f32)
{
    __shared__ __align__(16) unsigned char smraw[8192];  // [16 v][256 k] bf16 tile
    const int tid = threadIdx.x;
    const int wid = tid >> 6;            // wave id (phase B: nb group)
    const int lane = tid & 63;
    const int vl = tid & 15;             // vertex within tile
    const int h  = (tid >> 4) & 1;       // half-row (16 channels)
    const int as = tid >> 5;             // a-pair 0..3 -> a in {2as, 2as+1}
    const int vbase = blockIdx.x * MT;
    const unsigned short* xs = (const unsigned short*)xb;

    int vg = vbase + vl;
    int vc = vg < VN ? vg : VN - 1;
    const size_t ibase = (size_t)vc * 120 + as * 6;     // + r*24, in ints

    const int arow = lane & 15;      // phase-B A-frag row
    const int c0q = lane >> 4;       // phase-B 16B chunk

    f32x4 acc[4];
#pragma unroll
    for (int j = 0; j < 4; ++j) acc[j] = (f32x4)(0.f);

    i32x2 I[2][3];      // idx slots (6 ints), rotate by r&1
    f32x2 Wv[2][3];     // w slots, 1 ahead
    bf16x16 G[6];       // in-flight gathers (48 VGPR, held live)

    // ---------------- prologue: I(0), I(1), W(0); issue G(0) ----------------
#pragma unroll
    for (int q = 0; q < 3; ++q) {
        I[0][q]  = __builtin_nontemporal_load((const i32x2*)(bc_idx + ibase) + q);
        I[1][q]  = __builtin_nontemporal_load((const i32x2*)(bc_idx + ibase + 24) + q);
        Wv[0][q] = __builtin_nontemporal_load((const f32x2*)(bc_w  + ibase) + q);
    }
    __builtin_amdgcn_sched_barrier(0);
#pragma unroll
    for (int e = 0; e < 6; ++e) {
        int idx = I[0][e >> 1][e & 1];
        G[e] = *(const bf16x16*)(xs + (size_t)idx * CN + h * 16);
    }
    __builtin_amdgcn_sched_barrier(0);

#pragma unroll
    for (int r = 0; r < RN; ++r) {
        // -- prefetch idx (r+2) and w (r+1): issue-only, pinned above consume --
        if (r + 2 < RN) {
#pragma unroll
            for (int q = 0; q < 3; ++q)
                I[r & 1][q] = __builtin_nontemporal_load(
                    (const i32x2*)(bc_idx + ibase + (r + 2) * 24) + q);
        }
        if (r + 1 < RN) {
#pragma unroll
            for (int q = 0; q < 3; ++q)
                Wv[(r + 1) & 1][q] = __builtin_nontemporal_load(
                    (const f32x2*)(bc_w + ibase + (r + 1) * 24) + q);
        }
        __builtin_amdgcn_sched_barrier(0);

        // -- consume: blend G(r) -> swizzled LDS tile [16 v][256 k] bf16 --
#pragma unroll
        for (int aa = 0; aa < 2; ++aa) {
            const int a = as * 2 + aa;
            float w0 = Wv[r & 1][(aa * 3 + 0) >> 1][(aa * 3 + 0) & 1];
            float w1 = Wv[r & 1][(aa * 3 + 1) >> 1][(aa * 3 + 1) & 1];
            float w2 = Wv[r & 1][(aa * 3 + 2) >> 1][(aa * 3 + 2) & 1];
            bf16x8 ch[2];
#pragma unroll
            for (int j = 0; j < 16; ++j) {
                float f = fmaf(w0, b2f(G[aa * 3 + 0][j]),
                         fmaf(w1, b2f(G[aa * 3 + 1][j]),
                               w2 * b2f(G[aa * 3 + 2][j])));
                ch[j >> 3][j & 7] = f2b(f);
            }
#pragma unroll
            for (int qq = 0; qq < 2; ++qq) {
                int baddr = vl * 512 + ((a * 64 + h * 32 + qq * 16) ^ ((vl & 7) << 4));
                *(bf16x8*)(smraw + baddr) = ch[qq];
            }
        }
        __syncthreads();

        // -- issue gathers for r+1 (fly during phase B) --
        if (r + 1 < RN) {
#pragma unroll
            for (int e = 0; e < 6; ++e) {
                int idx = I[(r + 1) & 1][e >> 1][e & 1];
                G[e] = *(const bf16x16*)(xs + (size_t)idx * CN + h * 16);
            }
            __builtin_amdgcn_sched_barrier(0);
        }

        // -- phase B: MFMA from LDS; wave owns nb = wid*4 .. wid*4+3 --
#pragma unroll
        for (int ks = 0; ks < 8; ++ks) {
            int baddr = arow * 512 + ((ks * 64 + c0q * 16) ^ ((arow & 7) << 4));
            bf16x8 af = *(const bf16x8*)(smraw + baddr);
            int gks = r * 8 + ks;
#pragma unroll
            for (int j = 0; j < 4; ++j) {
                int nb = wid * 4 + j;
                bf16x8 bfr = *(const bf16x8*)((const unsigned short*)Bp +
                                ((size_t)(gks * NB + nb) * 64 + lane) * 8);
                acc[j] = __builtin_amdgcn_mfma_f32_16x16x32_bf16(af, bfr, acc[j], 0, 0, 0);
            }
        }
        __syncthreads();
    }

    // ---- AMP: per-wave partial max over this wave's 2 n's, then cross-wave ----
    f32x4* redp = (f32x4*)smraw;     // [wid 2][q 2][lane 64] f32x4 = 4 KB
#pragma unroll
    for (int q = 0; q < 2; ++q) {
        f32x4 pm;
#pragma unroll
        for (int rg = 0; rg < 4; ++rg)
            pm[rg] = fmaxf(acc[q][rg], acc[q + 2][rg]);   // nb=q, q+2: same t-half
        redp[(wid * 2 + q) * 64 + lane] = pm;
    }
    __syncthreads();

    // ---- epilogue: wave wid handles t-half q=wid; bias(+residual)+relu+store ----
    const int colD = lane & 15;
    const int rbase = (lane >> 4) << 2;
    {
        const int q = wid;
        f32x4 m0 = redp[(0 * 2 + q) * 64 + lane];
        f32x4 m1 = redp[(1 * 2 + q) * 64 + lane];
        int t = q * 16 + colD;
        float b = bias[t];
#pragma unroll
        for (int rg = 0; rg < 4; ++rg) {
            int vv = vbase + rbase + rg;
            if (vv < VN) {
                float val = fmaxf(m0[rg], m1[rg]) + b;
                if (FIRST) {
                    ((unsigned short*)out_bf)[vv * CN + t] =
                        (unsigned short)f2b(fmaxf(val, 0.f));   // reused by conv2 -> keep in L2
                } else {
                    val += __builtin_nontemporal_load(signal + vv * CN + t);
                    __builtin_nontemporal_store(fmaxf(val, 0.f), out_f + vv * CN + t);
                }
            }
        }
    }
}

extern "C" void kernel_launch(void* const* d_in, const int* in_sizes, int n_in,
                              void* d_out, int out_size, void* d_ws, size_t ws_size,
                              hipStream_t stream) {
    const float* signal = (const float*)d_in[0];
    const int*   bc_idx = (const int*)d_in[1];
    const float* bc_w   = (const float*)d_in[2];
    const float* t1     = (const float*)d_in[3];
    const float* b1     = (const float*)d_in[4];
    const float* t2     = (const float*)d_in[5];
    const float* b2     = (const float*)d_in[6];
    float* out = (float*)d_out;

    __hip_bfloat16* ws = (__hip_bfloat16*)d_ws;
    __hip_bfloat16* xb  = ws;                       // V*32 bf16
    __hip_bfloat16* s1  = ws + VN * CN;             // V*32 bf16
    __hip_bfloat16* Bp1 = ws + 2 * VN * CN;         // 163840 bf16
    __hip_bfloat16* Bp2 = Bp1 + RN * AN * NB * 64 * 8;
    // total ws use ~= 7.0 MB

    pack_x<<<(VN * CN / 4 + 255) / 256, 256, 0, stream>>>(signal, xb, VN * CN / 4);
    build_Bp<<<(RN * AN * NB * 64 * 8) / 256, 256, 0, stream>>>(t1, t2, Bp1, Bp2);

    int blocks = (VN + MT - 1) / MT;   // 3125 blocks, 128 threads (2 waves)
    conv_fused<true ><<<blocks, 128, 0, stream>>>(xb, bc_idx, bc_w, Bp1, b1, nullptr, s1, nullptr);
    conv_fused<false><<<blocks, 128, 0, stream>>>(s1, bc_idx, bc_w, Bp2, b2, signal, nullptr, out);
}